// Round 6
// baseline (1802.276 us; speedup 1.0000x reference)
//
#include <hip/hip_runtime.h>
#include <stdint.h>

#define NEGV -1e30f
static constexpr int BATCH = 64;
static constexpr int NN = 512;
static constexpr int MM = 512;
static constexpr int NM = NN * MM;
static constexpr size_t TOTAL = (size_t)BATCH * NM;
static constexpr int ROTC = 11;   // per-batch skew-row rotation (kept, neutral)

typedef float f32x4 __attribute__((ext_vector_type(4)));

// physical row of logical skew-row k for batch b (bijective per batch).
__device__ __forceinline__ int prow(int b, int k) {
    return (k + ROTC * b) & 511;
}

// lane n <- lane n-1 (whole-wave shift right by 1), 1 VALU op, no LDS.
__device__ __forceinline__ float wave_shr1(float x) {
    int y = __builtin_amdgcn_mov_dpp(__float_as_int(x), 0x138, 0xf, 0xf, true);
    return __int_as_float(y);
}

// compile-time float4 component select (folds after macro expansion)
#define F4C(v, c) ((c) == 0 ? (v).x : (c) == 1 ? (v).y : (c) == 2 ? (v).z : (v).w)

// XOR-swizzled LDS address for 64-float rows (transpose kernels only)
__device__ __forceinline__ int swz(int row, int c) {
    return row * 64 + ((((c >> 2) ^ (row & 15)) << 2) | (c & 3));
}

// ---------------------------------------------------------------------------
// block-level max reduction (256 threads)
// ---------------------------------------------------------------------------
__device__ inline float blockMax256(float v) {
    __shared__ float sm[256];
    sm[threadIdx.x] = v;
    __syncthreads();
    for (int s = 128; s > 0; s >>= 1) {
        if ((int)threadIdx.x < s)
            sm[threadIdx.x] = fmaxf(sm[threadIdx.x], sm[threadIdx.x + s]);
        __syncthreads();
    }
    return sm[0];
}

// ===========================================================================
// Skew-transposed layout. S[prow(b,k')][r] = A[r][(k'-r)&511].
// ===========================================================================

// K0: S_D[b][prow(r+c)][r] = D[b][r][c]. Tiled via LDS (coalesced both sides).
__global__ __launch_bounds__(256) void skew_kernel(const float* __restrict__ D,
                                                   float* __restrict__ Sd) {
    __shared__ float lds[64 * 64];
    const int bi = blockIdx.x;
    const int b = bi >> 6;
    const int t = bi & 63;
    const int r0 = (t >> 3) * 64;
    const int c0 = (t & 7) * 64;
    const float* Db = D + (size_t)b * NM;
    float* So = Sd + (size_t)b * NM;
    {
        const int xg = (threadIdx.x & 15) * 4;
        const int y0 = threadIdx.x >> 4;
        for (int sw = 0; sw < 4; ++sw) {
            const int y = y0 + 16 * sw;
            const float4 v = *(const float4*)(Db + (size_t)(r0 + y) * MM + c0 + xg);
            *(float4*)(lds + swz(y, xg)) = v;
        }
    }
    __syncthreads();
    const int rp = (int)threadIdx.x & 63;
    const int s0 = (int)threadIdx.x >> 6;
    for (int it = 0; it < 32; ++it) {
        const int s = s0 + 4 * it;
        if (s >= 127) break;
        const int dcol = s - rp;
        if (dcol >= 0 && dcol < 64) {
            So[(size_t)prow(b, r0 + c0 + s) * MM + r0 + rp] = lds[swz(rp, dcol)];
        }
    }
}

// ---------------------------------------------------------------------------
// K1: wavefront DP in skew space, register-ring pipelined (inline-asm loads,
// counted vmcnt gate) -- DP body byte-identical to round 5 (verified).
// THIS ROUND'S CHANGE IS PURE TLP: 16 independent (batch,dir) problems per
// 1024-thread block (16 waves, 4 per SIMD, no barriers anywhere) so each
// wave's memory-wait window is filled by 3 other waves' issue. Rounds 0-5
// all ran 1 wave/SIMD; their invariant ~1600 cyc/step was per-wave latency
// with nothing resident to hide it.
// ---------------------------------------------------------------------------
#define LSE3(dg, up, lf, dd, out) do { \
    const float m_ = fmaxf(fmaxf((dg), (up)), (lf)); \
    const float mn_ = fminf(fminf((dg), (up)), (lf)); \
    const float md_ = __builtin_amdgcn_fmed3f((dg), (up), (lf)); \
    const float s_ = 1.f + __expf(mn_ - m_) + __expf(md_ - m_); \
    (out) = (dd) + m_ + __logf(s_); \
} while (0)

// d-component per local row c, static per DIR (bwd reads are col-reversed).
#define DC0(A, B) (DIR ? (B)[3] : (A)[0])
#define DC1(A, B) (DIR ? (B)[2] : (A)[1])
#define DC2(A, B) (DIR ? (B)[1] : (A)[2])
#define DC3(A, B) (DIR ? (B)[0] : (A)[3])
#define DC4(A, B) (DIR ? (A)[3] : (B)[0])
#define DC5(A, B) (DIR ? (A)[2] : (B)[1])
#define DC6(A, B) (DIR ? (A)[1] : (B)[2])
#define DC7(A, B) (DIR ? (A)[0] : (B)[3])

template <int DIR>
__device__ __forceinline__ void dp_skew_run(const float* __restrict__ Sdp,
                                            float* __restrict__ Sout,
                                            const int b, const int lane) {
    const int t8 = lane * 8;
    const bool l0 = (lane == 0);

    float pA0 = NEGV, pA1 = NEGV, pA2 = NEGV, pA3 = NEGV,
          pA4 = NEGV, pA5 = NEGV, pA6 = NEGV, pA7 = NEGV;
    float pB0 = NEGV, pB1 = NEGV, pB2 = NEGV, pB3 = NEGV,
          pB4 = NEGV, pB5 = NEGV, pB6 = NEGV, pB7 = NEGV;
    f32x4 r0a, r0b, r1a, r1b, r2a, r2b, r3a, r3b,
          r4a, r4b, r5a, r5b, r6a, r6b, r7a, r7b;

// fire-and-forget asm loads of logical row kk into register pair (A,B).
#define RLOADA(kk, A, B) do { \
        const int lr_ = DIR ? (510 - (kk)) : (kk); \
        const float* rp_ = Sdp + (size_t)prow(b, lr_) * MM; \
        const float* pa_ = DIR ? (rp_ + 504 - t8) : (rp_ + t8); \
        const float* pb_ = DIR ? (rp_ + 508 - t8) : (rp_ + t8 + 4); \
        asm volatile("global_load_dwordx4 %0, %1, off" : "=v"(A) : "v"(pa_)); \
        asm volatile("global_load_dwordx4 %0, %1, off" : "=v"(B) : "v"(pb_)); \
    } while (0)

// counted gate: row k's loads (issued 8 steps ago) are guaranteed complete;
// sched_barrier keeps the register-only cell ops from hoisting above it.
#define GATE() do { \
        asm volatile("s_waitcnt vmcnt(14)" ::: "memory"); \
        __builtin_amdgcn_sched_barrier(0); \
    } while (0)

#define STEP(PH, PA, PB, RA, RB) do { \
        const int k = kb + (PH); \
        GATE(); \
        const float ups_ = wave_shr1(PA##7); \
        const float dgs_ = wave_shr1(PB##7); \
        const float up0_ = l0 ? NEGV : ups_; \
        const float dg0_ = l0 ? ((k == 0) ? 0.f : NEGV) : dgs_; \
        const float g1_ = PB##0, g2_ = PB##1, g3_ = PB##2, g4_ = PB##3, \
                    g5_ = PB##4, g6_ = PB##5, g7_ = PB##6; \
        LSE3(dg0_, up0_, PA##0, DC0(RA, RB), PB##0); \
        LSE3(g1_, PA##0, PA##1, DC1(RA, RB), PB##1); \
        LSE3(g2_, PA##1, PA##2, DC2(RA, RB), PB##2); \
        LSE3(g3_, PA##2, PA##3, DC3(RA, RB), PB##3); \
        LSE3(g4_, PA##3, PA##4, DC4(RA, RB), PB##4); \
        LSE3(g5_, PA##4, PA##5, DC5(RA, RB), PB##5); \
        LSE3(g6_, PA##5, PA##6, DC6(RA, RB), PB##6); \
        LSE3(g7_, PA##6, PA##7, DC7(RA, RB), PB##7); \
        { \
            const int kt_ = k - t8; \
            float* sp_ = Sout + (size_t)prow(b, k) * MM + t8; \
            if (kt_ >= 3 && kt_ <= 511) { \
                *(float4*)sp_ = make_float4(PB##0, PB##1, PB##2, PB##3); \
            } else if (kt_ >= 0 && kt_ <= 514) { \
                if (kt_ <= 511)             sp_[0] = PB##0; \
                if (kt_ >= 1 && kt_ <= 512) sp_[1] = PB##1; \
                if (kt_ >= 2 && kt_ <= 513) sp_[2] = PB##2; \
                if (kt_ >= 3)               sp_[3] = PB##3; \
            } \
            if (kt_ >= 7 && kt_ <= 515) { \
                *(float4*)(sp_ + 4) = make_float4(PB##4, PB##5, PB##6, PB##7); \
            } else if (kt_ >= 4 && kt_ <= 518) { \
                if (kt_ <= 515)             sp_[4] = PB##4; \
                if (kt_ >= 5 && kt_ <= 516) sp_[5] = PB##5; \
                if (kt_ >= 6 && kt_ <= 517) sp_[6] = PB##6; \
                if (kt_ >= 7)               sp_[7] = PB##7; \
            } \
        } \
        RLOADA(k + 8, RA, RB);   /* refill the just-consumed ring slot */ \
    } while (0)

    // prologue: fill the 8-deep register ring (16 asm loads in flight)
    RLOADA(0, r0a, r0b); RLOADA(1, r1a, r1b);
    RLOADA(2, r2a, r2b); RLOADA(3, r3a, r3b);
    RLOADA(4, r4a, r4b); RLOADA(5, r5a, r5b);
    RLOADA(6, r6a, r6b); RLOADA(7, r7a, r7b);

    for (int kb = 0; kb < NN + MM; kb += 8) {
        STEP(0, pA, pB, r0a, r0b);
        STEP(1, pB, pA, r1a, r1b);
        STEP(2, pA, pB, r2a, r2b);
        STEP(3, pB, pA, r3a, r3b);
        STEP(4, pA, pB, r4a, r4b);
        STEP(5, pB, pA, r5a, r5b);
        STEP(6, pA, pB, r6a, r6b);
        STEP(7, pB, pA, r7a, r7b);
    }

#undef STEP
#undef GATE
#undef RLOADA
}

// 1024 threads = 16 waves = 16 independent (batch,dir) problems, 4 waves/SIMD.
// No barriers in the DP path -> waves drift and hide each other's latency.
__global__ __launch_bounds__(1024, 1) void dp_skew_kernel(const float* __restrict__ Sd,
                                                          float* __restrict__ Sf,
                                                          float* __restrict__ Sb) {
    const int wid = (int)threadIdx.x >> 6;
    const int lane = (int)threadIdx.x & 63;
    const int p = blockIdx.x * 16 + wid;   // 8 blocks x 16 = 128 problems
    const int b = p & (BATCH - 1);
    const int dir = p >> 6;                // wave-uniform
    const float* Sdb = Sd + (size_t)b * NM;
    if (dir) dp_skew_run<1>(Sdb, Sb + (size_t)b * NM, b, lane);
    else     dp_skew_run<0>(Sdb, Sf + (size_t)b * NM, b, lane);
}

// K2': logit in skew space (logical rows; all arrays share the prow mapping).
__global__ __launch_bounds__(256) void logit_skew_kernel(float* __restrict__ Sd,
                                                         const float* __restrict__ Sf,
                                                         const float* __restrict__ Sb,
                                                         float* __restrict__ partial) {
    const size_t n4 = TOTAL / 4;
    float mx = NEGV;
    const size_t stride = (size_t)gridDim.x * blockDim.x;
    for (size_t e = (size_t)blockIdx.x * blockDim.x + threadIdx.x; e < n4; e += stride) {
        const int b = (int)(e >> 16);           // NM/4 = 65536
        const int rem = (int)(e & 65535);
        const int kp = rem >> 7;                // logical skew row
        const int r4 = (rem & 127) << 2;        // col group
        const size_t base = (size_t)b * NM;
        const size_t idx = base + (size_t)prow(b, kp) * MM + r4;
        const float4 f = *(const float4*)(Sf + idx);
        const float4 d = *(const float4*)(Sd + idx);
        const int k2 = (510 - kp) & 511;
        const float4 bb = *(const float4*)(Sb + base + (size_t)prow(b, k2) * MM + (508 - r4));
        float4 v;
        v.x = f.x + bb.w - d.x;
        v.y = f.y + bb.z - d.y;
        v.z = f.z + bb.y - d.z;
        v.w = f.w + bb.x - d.w;
        *(float4*)(Sd + idx) = v;
        mx = fmaxf(mx, fmaxf(fmaxf(v.x, v.y), fmaxf(v.z, v.w)));
    }
    float bm = blockMax256(mx);
    if (threadIdx.x == 0) partial[blockIdx.x] = bm;
}

// K3: reduce partials to one scalar
__global__ __launch_bounds__(256) void finalmax_kernel(const float* __restrict__ partial,
                                                       int n,
                                                       float* __restrict__ outmax) {
    float mx = NEGV;
    for (int i = threadIdx.x; i < n; i += 256) mx = fmaxf(mx, partial[i]);
    float bm = blockMax256(mx);
    if (threadIdx.x == 0) *outmax = bm;
}

// K4': unskew + subtract max. out[i][j] = OS[(i+j) logical][i] - mx. Tiled LDS.
__global__ __launch_bounds__(256) void unskew_kernel(const float* __restrict__ OS,
                                                     float* __restrict__ out,
                                                     const float* __restrict__ maxp) {
    __shared__ float lds[127 * 64];
    const float mx = *maxp;
    const int bi = blockIdx.x;
    const int b = bi >> 6;
    const int t = bi & 63;
    const int i0 = (t >> 3) * 64;
    const int j0 = (t & 7) * 64;
    const float* Ob = OS + (size_t)b * NM;
    float* ob = out + (size_t)b * NM;
    const int base = i0 + j0;
    {
        const int xg = ((int)threadIdx.x & 15) * 4;
        const int s0 = (int)threadIdx.x >> 4;
        for (int sw = 0; sw < 8; ++sw) {
            const int s = s0 + 16 * sw;
            if (s < 127) {
                const float4 v = *(const float4*)(Ob + (size_t)prow(b, base + s) * MM + i0 + xg);
                *(float4*)(lds + swz(s, xg)) = v;
            }
        }
    }
    __syncthreads();
    const int x4 = ((int)threadIdx.x & 15) * 4;   // j - j0 group
    const int y0 = (int)threadIdx.x >> 4;         // i - i0
    for (int sw = 0; sw < 4; ++sw) {
        const int y = y0 + 16 * sw;
        float4 v;
        v.x = lds[swz(x4 + 0 + y, y)] - mx;
        v.y = lds[swz(x4 + 1 + y, y)] - mx;
        v.z = lds[swz(x4 + 2 + y, y)] - mx;
        v.w = lds[swz(x4 + 3 + y, y)] - mx;
        *(float4*)(ob + (size_t)(i0 + y) * MM + j0 + x4) = v;
    }
}

// ===========================================================================
// LEGACY PATH (round-0, known-good): used only if ws_size < 128MB + slack.
// ===========================================================================
template <int DIR>
__device__ __forceinline__ void dp_run_legacy(const float* __restrict__ Db,
                                              float* __restrict__ Rp, int lane) {
    const int i0 = lane * 8;
    const bool l0 = (lane == 0);
    const float dgb0 = l0 ? 0.f : NEGV;

#define PTRS(r) \
    const float* ldp_##r = DIR ? (Db + (size_t)(NM - 1) - (size_t)(i0 + r) * MM) \
                               : (Db + (size_t)(i0 + r) * MM); \
    float* stp_##r = DIR ? (Rp + (size_t)(NM - 1) - (size_t)(i0 + r) * MM) \
                         : (Rp + (size_t)(i0 + r) * MM);
    PTRS(0) PTRS(1) PTRS(2) PTRS(3) PTRS(4) PTRS(5) PTRS(6) PTRS(7)

#define LOADG(r, dst, jgexpr) do { \
        int jc_ = (jgexpr); \
        jc_ = jc_ < 0 ? 0 : jc_; jc_ = jc_ > (MM - 4) ? (MM - 4) : jc_; \
        if (DIR) { const float4 t_ = *(const float4*)(ldp_##r - jc_ - 3); \
                   dst = make_float4(t_.w, t_.z, t_.y, t_.x); } \
        else     { dst = *(const float4*)(ldp_##r + jc_); } \
    } while (0)

#define INIT(r) \
    float p1_##r = NEGV, p2_##r = NEGV, p3_##r = NEGV, np_##r = NEGV; \
    float4 dc_##r, dn_##r; \
    LOADG(r, dn_##r, 0); dc_##r = dn_##r;
    INIT(0) INIT(1) INIT(2) INIT(3) INIT(4) INIT(5) INIT(6) INIT(7)

#define SWAPLOAD(r) do { dc_##r = dn_##r; LOADG(r, dn_##r, jj - (r) + 4); } while (0)

#define CELL(r, KK, DGIN, UPIN, DGB) do { \
        const int j_ = jj - (r); \
        const bool jz_ = (j_ == 0); \
        const float dg_ = jz_ ? (DGB) : (DGIN); \
        const float up_ = (UPIN); \
        const float lf_ = jz_ ? NEGV : p1_##r; \
        const float m_  = fmaxf(fmaxf(dg_, up_), lf_); \
        const float mn_ = fminf(fminf(dg_, up_), lf_); \
        const float md_ = __builtin_amdgcn_fmed3f(dg_, up_, lf_); \
        const float s_  = 1.f + __expf(mn_ - m_) + __expf(md_ - m_); \
        np_##r = F4C(dc_##r, ((KK) - (r)) & 3) + m_ + __logf(s_); \
    } while (0)

#define STORE(r) do { \
        const int j_ = jj - (r); \
        if (j_ >= 3 && j_ < MM) { \
            if (DIR) *(float4*)(stp_##r - j_) = \
                make_float4(np_##r, p1_##r, p2_##r, p3_##r); \
            else     *(float4*)(stp_##r + j_ - 3) = \
                make_float4(p3_##r, p2_##r, p1_##r, np_##r); \
        } \
    } while (0)

#define SHIFT(r) do { p3_##r = p2_##r; p2_##r = p1_##r; p1_##r = np_##r; } while (0)

#define LSTEP(KK, LA, LB, SA, SB) do { \
        const int jj = kbj + (KK); \
        SWAPLOAD(LA); SWAPLOAD(LB); \
        const float ups_ = wave_shr1(p1_7); \
        const float dgs_ = wave_shr1(p2_7); \
        const float up0r = l0 ? NEGV : ups_; \
        const float dg0r = l0 ? NEGV : dgs_; \
        CELL(0, KK, dg0r, up0r, dgb0); \
        CELL(1, KK, p2_0, p1_0, NEGV); \
        CELL(2, KK, p2_1, p1_1, NEGV); \
        CELL(3, KK, p2_2, p1_2, NEGV); \
        CELL(4, KK, p2_3, p1_3, NEGV); \
        CELL(5, KK, p2_4, p1_4, NEGV); \
        CELL(6, KK, p2_5, p1_5, NEGV); \
        CELL(7, KK, p2_6, p1_6, NEGV); \
        STORE(SA); STORE(SB); \
        SHIFT(0); SHIFT(1); SHIFT(2); SHIFT(3); \
        SHIFT(4); SHIFT(5); SHIFT(6); SHIFT(7); \
    } while (0)

    for (int kb = 0; kb < NN + MM; kb += 4) {
        const int kbj = kb - i0;
        LSTEP(0, 0, 4, 1, 5);
        LSTEP(1, 1, 5, 2, 6);
        LSTEP(2, 2, 6, 3, 7);
        LSTEP(3, 3, 7, 0, 4);
    }

#undef PTRS
#undef LOADG
#undef INIT
#undef SWAPLOAD
#undef CELL
#undef STORE
#undef SHIFT
#undef LSTEP
}

__global__ __launch_bounds__(64, 1) void dp_kernel_legacy(const float* __restrict__ D,
                                                          float* __restrict__ Rf,
                                                          float* __restrict__ Rb) {
    const int blk = blockIdx.x;
    const int b = blk & (BATCH - 1);
    const int dir = blk >> 6;
    const float* __restrict__ Db = D + (size_t)b * NM;
    const int lane = (int)threadIdx.x;
    if (dir) dp_run_legacy<1>(Db, Rb + (size_t)b * NM, lane);
    else     dp_run_legacy<0>(Db, Rf + (size_t)b * NM, lane);
}

__global__ __launch_bounds__(256) void logit_kernel(const float4* __restrict__ D,
                                                    const float4* __restrict__ Rb,
                                                    float4* __restrict__ out,
                                                    float* __restrict__ partial) {
    const size_t n4 = TOTAL / 4;
    float mx = NEGV;
    const size_t stride = (size_t)gridDim.x * blockDim.x;
    for (size_t idx = (size_t)blockIdx.x * blockDim.x + threadIdx.x; idx < n4;
         idx += stride) {
        float4 f = out[idx], bb = Rb[idx], d = D[idx];
        float4 v = make_float4(f.x + bb.x - d.x, f.y + bb.y - d.y,
                               f.z + bb.z - d.z, f.w + bb.w - d.w);
        out[idx] = v;
        mx = fmaxf(mx, fmaxf(fmaxf(v.x, v.y), fmaxf(v.z, v.w)));
    }
    float bm = blockMax256(mx);
    if (threadIdx.x == 0) partial[blockIdx.x] = bm;
}

__global__ __launch_bounds__(256) void sub_kernel(float4* __restrict__ out,
                                                  const float* __restrict__ maxp) {
    const float mx = *maxp;
    const size_t n4 = TOTAL / 4;
    const size_t stride = (size_t)gridDim.x * blockDim.x;
    for (size_t idx = (size_t)blockIdx.x * blockDim.x + threadIdx.x; idx < n4;
         idx += stride) {
        float4 v = out[idx];
        v.x -= mx; v.y -= mx; v.z -= mx; v.w -= mx;
        out[idx] = v;
    }
}

extern "C" void kernel_launch(void* const* d_in, const int* in_sizes, int n_in,
                              void* d_out, int out_size, void* d_ws, size_t ws_size,
                              hipStream_t stream) {
    const float* D = (const float*)d_in[0];
    float* out = (float*)d_out;

    const size_t needed = (2 * TOTAL + 4096) * sizeof(float);
    if (ws_size >= needed) {
        float* Sd = (float*)d_ws;
        float* Sb = Sd + TOTAL;
        float* partial = Sd + 2 * TOTAL;
        float* maxp = partial + 2048;

        skew_kernel<<<4096, 256, 0, stream>>>(D, Sd);
        dp_skew_kernel<<<8, 1024, 0, stream>>>(Sd, out, Sb);
        logit_skew_kernel<<<2048, 256, 0, stream>>>(Sd, out, Sb, partial);
        finalmax_kernel<<<1, 256, 0, stream>>>(partial, 2048, maxp);
        unskew_kernel<<<4096, 256, 0, stream>>>(Sd, out, maxp);
    } else {
        float* Rb = (float*)d_ws;
        float* partial = Rb + TOTAL;
        float* maxp = partial + 2048;

        dp_kernel_legacy<<<128, 64, 0, stream>>>(D, out, Rb);
        logit_kernel<<<2048, 256, 0, stream>>>((const float4*)D, (const float4*)Rb,
                                               (float4*)out, partial);
        finalmax_kernel<<<1, 256, 0, stream>>>(partial, 2048, maxp);
        sub_kernel<<<2048, 256, 0, stream>>>((float4*)out, maxp);
    }
}

// Round 7
// 703.248 us; speedup vs baseline: 2.5628x; 2.5628x over previous
//
#include <hip/hip_runtime.h>
#include <stdint.h>

#define NEGV -1e30f
static constexpr int BATCH = 64;
static constexpr int NN = 512;
static constexpr int MM = 512;
static constexpr int NM = NN * MM;
static constexpr size_t TOTAL = (size_t)BATCH * NM;
static constexpr int ROTC = 11;   // per-batch skew-row rotation (kept, neutral)

typedef float f32x4 __attribute__((ext_vector_type(4)));

// physical row of logical skew-row k for batch b (bijective per batch).
__device__ __forceinline__ int prow(int b, int k) {
    return (k + ROTC * b) & 511;
}

// lane n <- lane n-1 (whole-wave shift right by 1), 1 VALU op, no LDS.
__device__ __forceinline__ float wave_shr1(float x) {
    int y = __builtin_amdgcn_mov_dpp(__float_as_int(x), 0x138, 0xf, 0xf, true);
    return __int_as_float(y);
}

// compile-time float4 component select (folds after macro expansion)
#define F4C(v, c) ((c) == 0 ? (v).x : (c) == 1 ? (v).y : (c) == 2 ? (v).z : (v).w)

// XOR-swizzled LDS address for 64-float rows (transpose kernels only)
__device__ __forceinline__ int swz(int row, int c) {
    return row * 64 + ((((c >> 2) ^ (row & 15)) << 2) | (c & 3));
}

// group swizzle for the DP ring: float4-group g -> g ^ ((g>>1)&7).
// Bijective on [0,128); consecutive-lane groups (g=2t, 2t+1) land on 8
// distinct bank-quads per 8 lanes -> conflict-free ds_write/read_b128.
__device__ __forceinline__ int gswz(int g) {
    return g ^ ((g >> 1) & 7);
}

// ---------------------------------------------------------------------------
// block-level max reduction (256 threads)
// ---------------------------------------------------------------------------
__device__ inline float blockMax256(float v) {
    __shared__ float sm[256];
    sm[threadIdx.x] = v;
    __syncthreads();
    for (int s = 128; s > 0; s >>= 1) {
        if ((int)threadIdx.x < s)
            sm[threadIdx.x] = fmaxf(sm[threadIdx.x], sm[threadIdx.x + s]);
        __syncthreads();
    }
    return sm[0];
}

// ===========================================================================
// Skew-transposed layout. S[prow(b,k')][r] = A[r][(k'-r)&511].
// ===========================================================================

// K0: S_D[b][prow(r+c)][r] = D[b][r][c]. Tiled via LDS (coalesced both sides).
__global__ __launch_bounds__(256) void skew_kernel(const float* __restrict__ D,
                                                   float* __restrict__ Sd) {
    __shared__ float lds[64 * 64];
    const int bi = blockIdx.x;
    const int b = bi >> 6;
    const int t = bi & 63;
    const int r0 = (t >> 3) * 64;
    const int c0 = (t & 7) * 64;
    const float* Db = D + (size_t)b * NM;
    float* So = Sd + (size_t)b * NM;
    {
        const int xg = (threadIdx.x & 15) * 4;
        const int y0 = threadIdx.x >> 4;
        for (int sw = 0; sw < 4; ++sw) {
            const int y = y0 + 16 * sw;
            const float4 v = *(const float4*)(Db + (size_t)(r0 + y) * MM + c0 + xg);
            *(float4*)(lds + swz(y, xg)) = v;
        }
    }
    __syncthreads();
    const int rp = (int)threadIdx.x & 63;
    const int s0 = (int)threadIdx.x >> 6;
    for (int it = 0; it < 32; ++it) {
        const int s = s0 + 4 * it;
        if (s >= 127) break;
        const int dcol = s - rp;
        if (dcol >= 0 && dcol < 64) {
            So[(size_t)prow(b, r0 + c0 + s) * MM + r0 + rp] = lds[swz(rp, dcol)];
        }
    }
}

// ---------------------------------------------------------------------------
// K1: producer/consumer wavefront DP.
// Wave 0 (producer): verified R5 DP body; loads via fire-and-forget asm
//   global_load_dwordx4 gated by OUR vmcnt(14) (now provably loads-only:
//   this wave issues NO other VMEM). Results go to a 32-row LDS ring via
//   conflict-free swizzled float4 ds_writes -- ds_write acks in ~30cy, so
//   the compiler's WAR waits on the result registers are cheap (this was
//   the hidden serializer: global-store WAR waits drained a ~store-ack
//   round trip EVERY step in rounds 0-5).
// Wave 1 (writer): drains ring -> global with the exact old guard logic,
//   8-deep register rotation, 8-32 rows behind. Its store-ack stalls are
//   off the DP critical path. Handshake: dprog/wprog LDS flags + s_sleep.
// ---------------------------------------------------------------------------
#define LSE3(dg, up, lf, dd, out) do { \
    const float m_ = fmaxf(fmaxf((dg), (up)), (lf)); \
    const float mn_ = fminf(fminf((dg), (up)), (lf)); \
    const float md_ = __builtin_amdgcn_fmed3f((dg), (up), (lf)); \
    const float s_ = 1.f + __expf(mn_ - m_) + __expf(md_ - m_); \
    (out) = (dd) + m_ + __logf(s_); \
} while (0)

// d-component per local row c, static per DIR (bwd reads are col-reversed).
#define DC0(A, B) (DIR ? (B)[3] : (A)[0])
#define DC1(A, B) (DIR ? (B)[2] : (A)[1])
#define DC2(A, B) (DIR ? (B)[1] : (A)[2])
#define DC3(A, B) (DIR ? (B)[0] : (A)[3])
#define DC4(A, B) (DIR ? (A)[3] : (B)[0])
#define DC5(A, B) (DIR ? (A)[2] : (B)[1])
#define DC6(A, B) (DIR ? (A)[1] : (B)[2])
#define DC7(A, B) (DIR ? (A)[0] : (B)[3])

template <int DIR>
__device__ __forceinline__ void dp_produce(const float* __restrict__ Sdp,
                                           const int b, const int lane,
                                           float* __restrict__ ring,
                                           volatile int* d_prog,
                                           volatile int* w_prog) {
    const int t8 = lane * 8;
    const bool l0 = (lane == 0);
    const int lg0 = gswz(2 * lane) * 4;       // float index of group 2t
    const int lg1 = gswz(2 * lane + 1) * 4;   // float index of group 2t+1

    float pA0 = NEGV, pA1 = NEGV, pA2 = NEGV, pA3 = NEGV,
          pA4 = NEGV, pA5 = NEGV, pA6 = NEGV, pA7 = NEGV;
    float pB0 = NEGV, pB1 = NEGV, pB2 = NEGV, pB3 = NEGV,
          pB4 = NEGV, pB5 = NEGV, pB6 = NEGV, pB7 = NEGV;
    f32x4 r0a, r0b, r1a, r1b, r2a, r2b, r3a, r3b,
          r4a, r4b, r5a, r5b, r6a, r6b, r7a, r7b;

// fire-and-forget asm loads of logical row kk into register pair (A,B).
#define RLOADA(kk, A, B) do { \
        const int lr_ = DIR ? (510 - (kk)) : (kk); \
        const float* rp_ = Sdp + (size_t)prow(b, lr_) * MM; \
        const float* pa_ = DIR ? (rp_ + 504 - t8) : (rp_ + t8); \
        const float* pb_ = DIR ? (rp_ + 508 - t8) : (rp_ + t8 + 4); \
        asm volatile("global_load_dwordx4 %0, %1, off" : "=v"(A) : "v"(pa_)); \
        asm volatile("global_load_dwordx4 %0, %1, off" : "=v"(B) : "v"(pb_)); \
    } while (0)

// counted gate: loads-only vmcnt (this wave issues no other VMEM).
#define GATE() do { \
        asm volatile("s_waitcnt vmcnt(14)" ::: "memory"); \
        __builtin_amdgcn_sched_barrier(0); \
    } while (0)

#define STEP(PH, PA, PB, RA, RB) do { \
        const int k = kb + (PH); \
        GATE(); \
        const float ups_ = wave_shr1(PA##7); \
        const float dgs_ = wave_shr1(PB##7); \
        const float up0_ = l0 ? NEGV : ups_; \
        const float dg0_ = l0 ? ((k == 0) ? 0.f : NEGV) : dgs_; \
        const float g1_ = PB##0, g2_ = PB##1, g3_ = PB##2, g4_ = PB##3, \
                    g5_ = PB##4, g6_ = PB##5, g7_ = PB##6; \
        LSE3(dg0_, up0_, PA##0, DC0(RA, RB), PB##0); \
        LSE3(g1_, PA##0, PA##1, DC1(RA, RB), PB##1); \
        LSE3(g2_, PA##1, PA##2, DC2(RA, RB), PB##2); \
        LSE3(g3_, PA##2, PA##3, DC3(RA, RB), PB##3); \
        LSE3(g4_, PA##3, PA##4, DC4(RA, RB), PB##4); \
        LSE3(g5_, PA##4, PA##5, DC5(RA, RB), PB##5); \
        LSE3(g6_, PA##5, PA##6, DC6(RA, RB), PB##6); \
        LSE3(g7_, PA##6, PA##7, DC7(RA, RB), PB##7); \
        { \
            float* lp_ = ring + ((k & 31) << 9); \
            *(float4*)(lp_ + lg0) = make_float4(PB##0, PB##1, PB##2, PB##3); \
            *(float4*)(lp_ + lg1) = make_float4(PB##4, PB##5, PB##6, PB##7); \
        } \
        RLOADA(k + 8, RA, RB); \
    } while (0)

    // prologue: fill the 8-deep register ring (16 asm loads in flight)
    RLOADA(0, r0a, r0b); RLOADA(1, r1a, r1b);
    RLOADA(2, r2a, r2b); RLOADA(3, r3a, r3b);
    RLOADA(4, r4a, r4b); RLOADA(5, r5a, r5b);
    RLOADA(6, r6a, r6b); RLOADA(7, r7a, r7b);

    for (int kb = 0; kb < NN + MM; kb += 8) {
        // backpressure: slots kb..kb+7 reuse rows kb-32..kb-25 -> writer
        // must have consumed them (wprog >= kb-25; check kb-24, stricter).
        while (*w_prog < kb - 24) __builtin_amdgcn_s_sleep(16);
        STEP(0, pA, pB, r0a, r0b);
        STEP(1, pB, pA, r1a, r1b);
        STEP(2, pA, pB, r2a, r2b);
        STEP(3, pB, pA, r3a, r3b);
        asm volatile("s_waitcnt lgkmcnt(0)" ::: "memory");  // ds_writes done
        *d_prog = kb + 3;
        STEP(4, pA, pB, r4a, r4b);
        STEP(5, pB, pA, r5a, r5b);
        STEP(6, pA, pB, r6a, r6b);
        STEP(7, pB, pA, r7a, r7b);
        asm volatile("s_waitcnt lgkmcnt(0)" ::: "memory");
        *d_prog = kb + 7;
    }

#undef STEP
#undef GATE
#undef RLOADA
}

// writer wave: direction-agnostic (skew-space stores are identical for both
// dirs; the reversal lives in K2's read mapping). Ports the verified guarded
// store logic of rounds 2-5 verbatim.
__device__ __forceinline__ void writer_run(float* __restrict__ Sout, const int b,
                                           const int lane,
                                           const float* __restrict__ ring,
                                           volatile int* d_prog,
                                           volatile int* w_prog) {
    const int t8 = lane * 8;
    const int lg0 = gswz(2 * lane) * 4;
    const int lg1 = gswz(2 * lane + 1) * 4;

    float4 v0_0, v1_0, v0_1, v1_1, v0_2, v1_2, v0_3, v1_3,
           v0_4, v1_4, v0_5, v1_5, v0_6, v1_6, v0_7, v1_7;

#define WROW(kk, V0, V1) do { \
        const int k_ = (kk); \
        const int slot_ = k_ & 31; \
        const float* lp_ = ring + (slot_ << 9); \
        V0 = *(const float4*)(lp_ + lg0); \
        V1 = *(const float4*)(lp_ + lg1); \
        const int kt_ = k_ - t8; \
        float* sp_ = Sout + (size_t)prow(b, k_) * MM + t8; \
        if (kt_ >= 3 && kt_ <= 511) { \
            *(float4*)sp_ = V0; \
        } else if (kt_ >= 0 && kt_ <= 514) { \
            if (kt_ <= 511)             sp_[0] = V0.x; \
            if (kt_ >= 1 && kt_ <= 512) sp_[1] = V0.y; \
            if (kt_ >= 2 && kt_ <= 513) sp_[2] = V0.z; \
            if (kt_ >= 3)               sp_[3] = V0.w; \
        } \
        if (kt_ >= 7 && kt_ <= 515) { \
            *(float4*)(sp_ + 4) = V1; \
        } else if (kt_ >= 4 && kt_ <= 518) { \
            if (kt_ <= 515)             sp_[4] = V1.x; \
            if (kt_ >= 5 && kt_ <= 516) sp_[5] = V1.y; \
            if (kt_ >= 6 && kt_ <= 517) sp_[6] = V1.z; \
            if (kt_ >= 7)               sp_[7] = V1.w; \
        } \
    } while (0)

    for (int k0 = 0; k0 < NN + MM; k0 += 8) {
        while (*d_prog < k0 + 7) __builtin_amdgcn_s_sleep(16);
        WROW(k0 + 0, v0_0, v1_0);
        WROW(k0 + 1, v0_1, v1_1);
        WROW(k0 + 2, v0_2, v1_2);
        WROW(k0 + 3, v0_3, v1_3);
        WROW(k0 + 4, v0_4, v1_4);
        WROW(k0 + 5, v0_5, v1_5);
        WROW(k0 + 6, v0_6, v1_6);
        WROW(k0 + 7, v0_7, v1_7);
        asm volatile("s_waitcnt lgkmcnt(0)" ::: "memory");  // ds_reads done
        *w_prog = k0 + 7;
    }
#undef WROW
}

__global__ __launch_bounds__(128, 1) void dp_skew_kernel(const float* __restrict__ Sd,
                                                         float* __restrict__ Sf,
                                                         float* __restrict__ Sb) {
    __shared__ float ring[32 * 512];   // 64 KB diagonal ring
    __shared__ int ctrl[2];            // [0]=dprog, [1]=wprog
    volatile int* d_prog = &ctrl[0];
    volatile int* w_prog = &ctrl[1];
    if (threadIdx.x == 0) { ctrl[0] = -1; ctrl[1] = -1; }
    __syncthreads();                   // only barrier; waves drift after this

    const int blk = blockIdx.x;
    const int b = blk & (BATCH - 1);
    const int dir = blk >> 6;
    const int wid = (int)threadIdx.x >> 6;
    const int lane = (int)threadIdx.x & 63;
    const float* Sdb = Sd + (size_t)b * NM;
    float* Sout = (dir ? Sb : Sf) + (size_t)b * NM;

    if (wid == 0) {
        if (dir) dp_produce<1>(Sdb, b, lane, ring, d_prog, w_prog);
        else     dp_produce<0>(Sdb, b, lane, ring, d_prog, w_prog);
    } else {
        writer_run(Sout, b, lane, ring, d_prog, w_prog);
    }
}

// K2': logit in skew space (logical rows; all arrays share the prow mapping).
__global__ __launch_bounds__(256) void logit_skew_kernel(float* __restrict__ Sd,
                                                         const float* __restrict__ Sf,
                                                         const float* __restrict__ Sb,
                                                         float* __restrict__ partial) {
    const size_t n4 = TOTAL / 4;
    float mx = NEGV;
    const size_t stride = (size_t)gridDim.x * blockDim.x;
    for (size_t e = (size_t)blockIdx.x * blockDim.x + threadIdx.x; e < n4; e += stride) {
        const int b = (int)(e >> 16);           // NM/4 = 65536
        const int rem = (int)(e & 65535);
        const int kp = rem >> 7;                // logical skew row
        const int r4 = (rem & 127) << 2;        // col group
        const size_t base = (size_t)b * NM;
        const size_t idx = base + (size_t)prow(b, kp) * MM + r4;
        const float4 f = *(const float4*)(Sf + idx);
        const float4 d = *(const float4*)(Sd + idx);
        const int k2 = (510 - kp) & 511;
        const float4 bb = *(const float4*)(Sb + base + (size_t)prow(b, k2) * MM + (508 - r4));
        float4 v;
        v.x = f.x + bb.w - d.x;
        v.y = f.y + bb.z - d.y;
        v.z = f.z + bb.y - d.z;
        v.w = f.w + bb.x - d.w;
        *(float4*)(Sd + idx) = v;
        mx = fmaxf(mx, fmaxf(fmaxf(v.x, v.y), fmaxf(v.z, v.w)));
    }
    float bm = blockMax256(mx);
    if (threadIdx.x == 0) partial[blockIdx.x] = bm;
}

// K3: reduce partials to one scalar
__global__ __launch_bounds__(256) void finalmax_kernel(const float* __restrict__ partial,
                                                       int n,
                                                       float* __restrict__ outmax) {
    float mx = NEGV;
    for (int i = threadIdx.x; i < n; i += 256) mx = fmaxf(mx, partial[i]);
    float bm = blockMax256(mx);
    if (threadIdx.x == 0) *outmax = bm;
}

// K4': unskew + subtract max. out[i][j] = OS[(i+j) logical][i] - mx. Tiled LDS.
__global__ __launch_bounds__(256) void unskew_kernel(const float* __restrict__ OS,
                                                     float* __restrict__ out,
                                                     const float* __restrict__ maxp) {
    __shared__ float lds[127 * 64];
    const float mx = *maxp;
    const int bi = blockIdx.x;
    const int b = bi >> 6;
    const int t = bi & 63;
    const int i0 = (t >> 3) * 64;
    const int j0 = (t & 7) * 64;
    const float* Ob = OS + (size_t)b * NM;
    float* ob = out + (size_t)b * NM;
    const int base = i0 + j0;
    {
        const int xg = ((int)threadIdx.x & 15) * 4;
        const int s0 = (int)threadIdx.x >> 4;
        for (int sw = 0; sw < 8; ++sw) {
            const int s = s0 + 16 * sw;
            if (s < 127) {
                const float4 v = *(const float4*)(Ob + (size_t)prow(b, base + s) * MM + i0 + xg);
                *(float4*)(lds + swz(s, xg)) = v;
            }
        }
    }
    __syncthreads();
    const int x4 = ((int)threadIdx.x & 15) * 4;   // j - j0 group
    const int y0 = (int)threadIdx.x >> 4;         // i - i0
    for (int sw = 0; sw < 4; ++sw) {
        const int y = y0 + 16 * sw;
        float4 v;
        v.x = lds[swz(x4 + 0 + y, y)] - mx;
        v.y = lds[swz(x4 + 1 + y, y)] - mx;
        v.z = lds[swz(x4 + 2 + y, y)] - mx;
        v.w = lds[swz(x4 + 3 + y, y)] - mx;
        *(float4*)(ob + (size_t)(i0 + y) * MM + j0 + x4) = v;
    }
}

// ===========================================================================
// LEGACY PATH (round-0, known-good): used only if ws_size < 128MB + slack.
// ===========================================================================
template <int DIR>
__device__ __forceinline__ void dp_run_legacy(const float* __restrict__ Db,
                                              float* __restrict__ Rp, int lane) {
    const int i0 = lane * 8;
    const bool l0 = (lane == 0);
    const float dgb0 = l0 ? 0.f : NEGV;

#define PTRS(r) \
    const float* ldp_##r = DIR ? (Db + (size_t)(NM - 1) - (size_t)(i0 + r) * MM) \
                               : (Db + (size_t)(i0 + r) * MM); \
    float* stp_##r = DIR ? (Rp + (size_t)(NM - 1) - (size_t)(i0 + r) * MM) \
                         : (Rp + (size_t)(i0 + r) * MM);
    PTRS(0) PTRS(1) PTRS(2) PTRS(3) PTRS(4) PTRS(5) PTRS(6) PTRS(7)

#define LOADG(r, dst, jgexpr) do { \
        int jc_ = (jgexpr); \
        jc_ = jc_ < 0 ? 0 : jc_; jc_ = jc_ > (MM - 4) ? (MM - 4) : jc_; \
        if (DIR) { const float4 t_ = *(const float4*)(ldp_##r - jc_ - 3); \
                   dst = make_float4(t_.w, t_.z, t_.y, t_.x); } \
        else     { dst = *(const float4*)(ldp_##r + jc_); } \
    } while (0)

#define INIT(r) \
    float p1_##r = NEGV, p2_##r = NEGV, p3_##r = NEGV, np_##r = NEGV; \
    float4 dc_##r, dn_##r; \
    LOADG(r, dn_##r, 0); dc_##r = dn_##r;
    INIT(0) INIT(1) INIT(2) INIT(3) INIT(4) INIT(5) INIT(6) INIT(7)

#define SWAPLOAD(r) do { dc_##r = dn_##r; LOADG(r, dn_##r, jj - (r) + 4); } while (0)

#define CELL(r, KK, DGIN, UPIN, DGB) do { \
        const int j_ = jj - (r); \
        const bool jz_ = (j_ == 0); \
        const float dg_ = jz_ ? (DGB) : (DGIN); \
        const float up_ = (UPIN); \
        const float lf_ = jz_ ? NEGV : p1_##r; \
        const float m_  = fmaxf(fmaxf(dg_, up_), lf_); \
        const float mn_ = fminf(fminf(dg_, up_), lf_); \
        const float md_ = __builtin_amdgcn_fmed3f(dg_, up_, lf_); \
        const float s_  = 1.f + __expf(mn_ - m_) + __expf(md_ - m_); \
        np_##r = F4C(dc_##r, ((KK) - (r)) & 3) + m_ + __logf(s_); \
    } while (0)

#define STORE(r) do { \
        const int j_ = jj - (r); \
        if (j_ >= 3 && j_ < MM) { \
            if (DIR) *(float4*)(stp_##r - j_) = \
                make_float4(np_##r, p1_##r, p2_##r, p3_##r); \
            else     *(float4*)(stp_##r + j_ - 3) = \
                make_float4(p3_##r, p2_##r, p1_##r, np_##r); \
        } \
    } while (0)

#define SHIFT(r) do { p3_##r = p2_##r; p2_##r = p1_##r; p1_##r = np_##r; } while (0)

#define LSTEP(KK, LA, LB, SA, SB) do { \
        const int jj = kbj + (KK); \
        SWAPLOAD(LA); SWAPLOAD(LB); \
        const float ups_ = wave_shr1(p1_7); \
        const float dgs_ = wave_shr1(p2_7); \
        const float up0r = l0 ? NEGV : ups_; \
        const float dg0r = l0 ? NEGV : dgs_; \
        CELL(0, KK, dg0r, up0r, dgb0); \
        CELL(1, KK, p2_0, p1_0, NEGV); \
        CELL(2, KK, p2_1, p1_1, NEGV); \
        CELL(3, KK, p2_2, p1_2, NEGV); \
        CELL(4, KK, p2_3, p1_3, NEGV); \
        CELL(5, KK, p2_4, p1_4, NEGV); \
        CELL(6, KK, p2_5, p1_5, NEGV); \
        CELL(7, KK, p2_6, p1_6, NEGV); \
        STORE(SA); STORE(SB); \
        SHIFT(0); SHIFT(1); SHIFT(2); SHIFT(3); \
        SHIFT(4); SHIFT(5); SHIFT(6); SHIFT(7); \
    } while (0)

    for (int kb = 0; kb < NN + MM; kb += 4) {
        const int kbj = kb - i0;
        LSTEP(0, 0, 4, 1, 5);
        LSTEP(1, 1, 5, 2, 6);
        LSTEP(2, 2, 6, 3, 7);
        LSTEP(3, 3, 7, 0, 4);
    }

#undef PTRS
#undef LOADG
#undef INIT
#undef SWAPLOAD
#undef CELL
#undef STORE
#undef SHIFT
#undef LSTEP
}

__global__ __launch_bounds__(64, 1) void dp_kernel_legacy(const float* __restrict__ D,
                                                          float* __restrict__ Rf,
                                                          float* __restrict__ Rb) {
    const int blk = blockIdx.x;
    const int b = blk & (BATCH - 1);
    const int dir = blk >> 6;
    const float* __restrict__ Db = D + (size_t)b * NM;
    const int lane = (int)threadIdx.x;
    if (dir) dp_run_legacy<1>(Db, Rb + (size_t)b * NM, lane);
    else     dp_run_legacy<0>(Db, Rf + (size_t)b * NM, lane);
}

__global__ __launch_bounds__(256) void logit_kernel(const float4* __restrict__ D,
                                                    const float4* __restrict__ Rb,
                                                    float4* __restrict__ out,
                                                    float* __restrict__ partial) {
    const size_t n4 = TOTAL / 4;
    float mx = NEGV;
    const size_t stride = (size_t)gridDim.x * blockDim.x;
    for (size_t idx = (size_t)blockIdx.x * blockDim.x + threadIdx.x; idx < n4;
         idx += stride) {
        float4 f = out[idx], bb = Rb[idx], d = D[idx];
        float4 v = make_float4(f.x + bb.x - d.x, f.y + bb.y - d.y,
                               f.z + bb.z - d.z, f.w + bb.w - d.w);
        out[idx] = v;
        mx = fmaxf(mx, fmaxf(fmaxf(v.x, v.y), fmaxf(v.z, v.w)));
    }
    float bm = blockMax256(mx);
    if (threadIdx.x == 0) partial[blockIdx.x] = bm;
}

__global__ __launch_bounds__(256) void sub_kernel(float4* __restrict__ out,
                                                  const float* __restrict__ maxp) {
    const float mx = *maxp;
    const size_t n4 = TOTAL / 4;
    const size_t stride = (size_t)gridDim.x * blockDim.x;
    for (size_t idx = (size_t)blockIdx.x * blockDim.x + threadIdx.x; idx < n4;
         idx += stride) {
        float4 v = out[idx];
        v.x -= mx; v.y -= mx; v.z -= mx; v.w -= mx;
        out[idx] = v;
    }
}

extern "C" void kernel_launch(void* const* d_in, const int* in_sizes, int n_in,
                              void* d_out, int out_size, void* d_ws, size_t ws_size,
                              hipStream_t stream) {
    const float* D = (const float*)d_in[0];
    float* out = (float*)d_out;

    const size_t needed = (2 * TOTAL + 4096) * sizeof(float);
    if (ws_size >= needed) {
        float* Sd = (float*)d_ws;
        float* Sb = Sd + TOTAL;
        float* partial = Sd + 2 * TOTAL;
        float* maxp = partial + 2048;

        skew_kernel<<<4096, 256, 0, stream>>>(D, Sd);
        dp_skew_kernel<<<128, 128, 0, stream>>>(Sd, out, Sb);
        logit_skew_kernel<<<2048, 256, 0, stream>>>(Sd, out, Sb, partial);
        finalmax_kernel<<<1, 256, 0, stream>>>(partial, 2048, maxp);
        unskew_kernel<<<4096, 256, 0, stream>>>(Sd, out, maxp);
    } else {
        float* Rb = (float*)d_ws;
        float* partial = Rb + TOTAL;
        float* maxp = partial + 2048;

        dp_kernel_legacy<<<128, 64, 0, stream>>>(D, out, Rb);
        logit_kernel<<<2048, 256, 0, stream>>>((const float4*)D, (const float4*)Rb,
                                               (float4*)out, partial);
        finalmax_kernel<<<1, 256, 0, stream>>>(partial, 2048, maxp);
        sub_kernel<<<2048, 256, 0, stream>>>((float4*)out, maxp);
    }
}

// Round 8
// 516.623 us; speedup vs baseline: 3.4886x; 1.3612x over previous
//
#include <hip/hip_runtime.h>
#include <stdint.h>

#define NEGV -1e30f
static constexpr int BATCH = 64;
static constexpr int NN = 512;
static constexpr int MM = 512;
static constexpr int NM = NN * MM;
static constexpr size_t TOTAL = (size_t)BATCH * NM;
static constexpr int ROTC = 11;   // per-batch skew-row rotation (kept, neutral)

typedef float f32x4 __attribute__((ext_vector_type(4)));

// physical row of logical skew-row k for batch b (bijective per batch).
// Works for negative k: two's-complement & gives [0,511].
__device__ __forceinline__ int prow(int b, int k) {
    return (k + ROTC * b) & 511;
}

// lane n <- lane n-1 (whole-wave shift right by 1), 1 VALU op, no LDS.
__device__ __forceinline__ float wave_shr1(float x) {
    int y = __builtin_amdgcn_mov_dpp(__float_as_int(x), 0x138, 0xf, 0xf, true);
    return __int_as_float(y);
}

// compile-time float4 component select (folds after macro expansion)
#define F4C(v, c) ((c) == 0 ? (v).x : (c) == 1 ? (v).y : (c) == 2 ? (v).z : (v).w)

// XOR-swizzled LDS address for 64-float rows (transpose kernels only)
__device__ __forceinline__ int swz(int row, int c) {
    return row * 64 + ((((c >> 2) ^ (row & 15)) << 2) | (c & 3));
}

// ---------------------------------------------------------------------------
// block-level max reduction (256 threads)
// ---------------------------------------------------------------------------
__device__ inline float blockMax256(float v) {
    __shared__ float sm[256];
    sm[threadIdx.x] = v;
    __syncthreads();
    for (int s = 128; s > 0; s >>= 1) {
        if ((int)threadIdx.x < s)
            sm[threadIdx.x] = fmaxf(sm[threadIdx.x], sm[threadIdx.x + s]);
        __syncthreads();
    }
    return sm[0];
}

// ===========================================================================
// Skew-transposed layout. S[prow(b,k')][r] = A[r][(k'-r)&511].
// ===========================================================================

// K0: S_D[b][prow(r+c)][r] = D[b][r][c]. Tiled via LDS (coalesced both sides).
__global__ __launch_bounds__(256) void skew_kernel(const float* __restrict__ D,
                                                   float* __restrict__ Sd) {
    __shared__ float lds[64 * 64];
    const int bi = blockIdx.x;
    const int b = bi >> 6;
    const int t = bi & 63;
    const int r0 = (t >> 3) * 64;
    const int c0 = (t & 7) * 64;
    const float* Db = D + (size_t)b * NM;
    float* So = Sd + (size_t)b * NM;
    {
        const int xg = (threadIdx.x & 15) * 4;
        const int y0 = threadIdx.x >> 4;
        for (int sw = 0; sw < 4; ++sw) {
            const int y = y0 + 16 * sw;
            const float4 v = *(const float4*)(Db + (size_t)(r0 + y) * MM + c0 + xg);
            *(float4*)(lds + swz(y, xg)) = v;
        }
    }
    __syncthreads();
    const int rp = (int)threadIdx.x & 63;
    const int s0 = (int)threadIdx.x >> 6;
    for (int it = 0; it < 32; ++it) {
        const int s = s0 + 4 * it;
        if (s >= 127) break;
        const int dcol = s - rp;
        if (dcol >= 0 && dcol < 64) {
            So[(size_t)prow(b, r0 + c0 + s) * MM + r0 + rp] = lds[swz(rp, dcol)];
        }
    }
}

// ---------------------------------------------------------------------------
// K1: 2-producer + writer wavefront DP.
// Wave A (half 0): rows 0..255, 4 rows/lane; wave B (half 1): rows 256..511.
// Each producer: 1 asm global_load_dwordx4/step (vmcnt(7) gate, 8-deep reg
// ring), 4 LSE3 cells, 1 ds_write_b128 into the 32-slot diagonal ring.
// A->B coupling: A lane63 publishes {np255(k), np255(k-1)} to a 32-slot LDS
// pair-ring each step; B lane0 consumes pair(k-1), prefetched 8/group.
// Sync: flag-based, one poll per 8-step group, no barriers. B runs exactly
// one group behind A. Writer wave drains ring->global (verified R7 logic).
// ---------------------------------------------------------------------------
#define LSE3(dg, up, lf, dd, out) do { \
    const float m_ = fmaxf(fmaxf((dg), (up)), (lf)); \
    const float mn_ = fminf(fminf((dg), (up)), (lf)); \
    const float md_ = __builtin_amdgcn_fmed3f((dg), (up), (lf)); \
    const float s_ = 1.f + __expf(mn_ - m_) + __expf(md_ - m_); \
    (out) = (dd) + m_ + __logf(s_); \
} while (0)

// d-component per local row i (0..3), static per DIR (bwd loads col-reversed).
#define D0(RV) (DIR ? (RV)[3] : (RV)[0])
#define D1(RV) (DIR ? (RV)[2] : (RV)[1])
#define D2(RV) (DIR ? (RV)[1] : (RV)[2])
#define D3(RV) (DIR ? (RV)[0] : (RV)[3])

template <int DIR, int HALF>
__device__ __forceinline__ void dp_half(const float* __restrict__ Sdp,
                                        const int b, const int lane,
                                        float* __restrict__ ring,
                                        float2* __restrict__ pring,
                                        volatile int* my_prog,
                                        volatile int* other_prog,
                                        volatile int* w_prog) {
    constexpr int R0 = HALF * 256;
    const int t4 = lane * 4;
    const bool l0 = (lane == 0);

    float pA0 = NEGV, pA1 = NEGV, pA2 = NEGV, pA3 = NEGV;
    float pB0 = NEGV, pB1 = NEGV, pB2 = NEGV, pB3 = NEGV;
    f32x4 r0, r1, r2, r3, r4, r5, r6, r7;

// fire-and-forget asm load of this half's quarter of logical row kk.
#define RLOAD(kk, RV) do { \
        const int lr_ = DIR ? (510 - (kk)) : (kk); \
        const float* rp_ = Sdp + (size_t)prow(b, lr_) * MM; \
        const float* pa_ = DIR ? (rp_ + 508 - R0 - t4) : (rp_ + R0 + t4); \
        asm volatile("global_load_dwordx4 %0, %1, off" : "=v"(RV) : "v"(pa_)); \
    } while (0)

// counted gate: loads-only vmcnt (this wave issues no other VMEM).
#define GATE() do { \
        asm volatile("s_waitcnt vmcnt(7)" ::: "memory"); \
        __builtin_amdgcn_sched_barrier(0); \
    } while (0)

#define STEP(PH, PA, PB, RV) do { \
        const int k = kb + (PH); \
        GATE(); \
        const float ups_ = wave_shr1(PA##3); \
        const float dgs_ = wave_shr1(PB##3); \
        float up0_, dg0_; \
        if constexpr (HALF == 0) { \
            up0_ = l0 ? NEGV : ups_; \
            dg0_ = l0 ? ((k == 0) ? 0.f : NEGV) : dgs_; \
        } else { \
            up0_ = l0 ? pr##PH.x : ups_; \
            dg0_ = l0 ? pr##PH.y : dgs_; \
        } \
        const float g1_ = PB##0, g2_ = PB##1, g3_ = PB##2; \
        LSE3(dg0_, up0_, PA##0, D0(RV), PB##0); \
        LSE3(g1_, PA##0, PA##1, D1(RV), PB##1); \
        LSE3(g2_, PA##1, PA##2, D2(RV), PB##2); \
        LSE3(g3_, PA##2, PA##3, D3(RV), PB##3); \
        *(float4*)(ring + ((k & 31) << 9) + R0 + t4) = \
            make_float4(PB##0, PB##1, PB##2, PB##3); \
        if constexpr (HALF == 0) { \
            if (lane == 63) pring[k & 31] = make_float2(PB##3, PA##3); \
        } \
        RLOAD(k + 8, RV); \
    } while (0)

    // prologue: fill the 8-deep register ring
    RLOAD(0, r0); RLOAD(1, r1); RLOAD(2, r2); RLOAD(3, r3);
    RLOAD(4, r4); RLOAD(5, r5); RLOAD(6, r6); RLOAD(7, r7);

    for (int kb = 0; kb < NN + MM; kb += 8) {
        if constexpr (HALF == 0) {
            // data-ring reuse (writer) + pair-ring reuse (B consumed old pairs)
            while (*w_prog < kb - 24 || *other_prog < kb - 24)
                __builtin_amdgcn_s_sleep(2);
        } else {
            // need A's pairs up to step kb+6, and data-ring slots free
            while (*other_prog < kb + 6 || *w_prog < kb - 24)
                __builtin_amdgcn_s_sleep(2);
        }
        asm volatile("" ::: "memory");
        float2 pr0 = make_float2(NEGV, NEGV), pr1 = pr0, pr2 = pr0, pr3 = pr0,
               pr4 = pr0, pr5 = pr0, pr6 = pr0, pr7 = pr0;
        if constexpr (HALF == 1) {
            pr0 = pring[(kb - 1) & 31]; pr1 = pring[(kb + 0) & 31];
            pr2 = pring[(kb + 1) & 31]; pr3 = pring[(kb + 2) & 31];
            pr4 = pring[(kb + 3) & 31]; pr5 = pring[(kb + 4) & 31];
            pr6 = pring[(kb + 5) & 31]; pr7 = pring[(kb + 6) & 31];
        }
        STEP(0, pA, pB, r0);
        STEP(1, pB, pA, r1);
        STEP(2, pA, pB, r2);
        STEP(3, pB, pA, r3);
        STEP(4, pA, pB, r4);
        STEP(5, pB, pA, r5);
        STEP(6, pA, pB, r6);
        STEP(7, pB, pA, r7);
        asm volatile("s_waitcnt lgkmcnt(0)" ::: "memory");  // ring+pair writes done
        if (l0) *my_prog = kb + 7;
    }

#undef STEP
#undef GATE
#undef RLOAD
}

// writer wave: drains ring -> global; verified R7 guarded-store logic
// (identity ring layout: lane t holds rows 8t..8t+7 via 2 float4 groups).
__device__ __forceinline__ void writer_run(float* __restrict__ Sout, const int b,
                                           const int lane,
                                           const float* __restrict__ ring,
                                           volatile int* a_prog,
                                           volatile int* b_prog,
                                           volatile int* w_prog) {
    const int t8 = lane * 8;
    const int lg0 = lane * 8;
    const int lg1 = lane * 8 + 4;

    float4 v0_0, v1_0, v0_1, v1_1, v0_2, v1_2, v0_3, v1_3,
           v0_4, v1_4, v0_5, v1_5, v0_6, v1_6, v0_7, v1_7;

#define WROW(kk, V0, V1) do { \
        const int k_ = (kk); \
        const float* lp_ = ring + ((k_ & 31) << 9); \
        V0 = *(const float4*)(lp_ + lg0); \
        V1 = *(const float4*)(lp_ + lg1); \
        const int kt_ = k_ - t8; \
        float* sp_ = Sout + (size_t)prow(b, k_) * MM + t8; \
        if (kt_ >= 3 && kt_ <= 511) { \
            *(float4*)sp_ = V0; \
        } else if (kt_ >= 0 && kt_ <= 514) { \
            if (kt_ <= 511)             sp_[0] = V0.x; \
            if (kt_ >= 1 && kt_ <= 512) sp_[1] = V0.y; \
            if (kt_ >= 2 && kt_ <= 513) sp_[2] = V0.z; \
            if (kt_ >= 3)               sp_[3] = V0.w; \
        } \
        if (kt_ >= 7 && kt_ <= 515) { \
            *(float4*)(sp_ + 4) = V1; \
        } else if (kt_ >= 4 && kt_ <= 518) { \
            if (kt_ <= 515)             sp_[4] = V1.x; \
            if (kt_ >= 5 && kt_ <= 516) sp_[5] = V1.y; \
            if (kt_ >= 6 && kt_ <= 517) sp_[6] = V1.z; \
            if (kt_ >= 7)               sp_[7] = V1.w; \
        } \
    } while (0)

    for (int k0 = 0; k0 < NN + MM; k0 += 8) {
        while (*a_prog < k0 + 7 || *b_prog < k0 + 7) __builtin_amdgcn_s_sleep(2);
        asm volatile("" ::: "memory");
        WROW(k0 + 0, v0_0, v1_0);
        WROW(k0 + 1, v0_1, v1_1);
        WROW(k0 + 2, v0_2, v1_2);
        WROW(k0 + 3, v0_3, v1_3);
        WROW(k0 + 4, v0_4, v1_4);
        WROW(k0 + 5, v0_5, v1_5);
        WROW(k0 + 6, v0_6, v1_6);
        WROW(k0 + 7, v0_7, v1_7);
        asm volatile("s_waitcnt lgkmcnt(0)" ::: "memory");  // ds_reads done
        if (lane == 0) *w_prog = k0 + 7;
    }
#undef WROW
}

__global__ __launch_bounds__(192, 1) void dp_skew_kernel(const float* __restrict__ Sd,
                                                         float* __restrict__ Sf,
                                                         float* __restrict__ Sb) {
    __shared__ float ring[32 * 512];   // 64 KB diagonal ring
    __shared__ float2 pring[32];       // A->B boundary pair ring
    __shared__ int ctrl[3];            // [0]=a_prog, [1]=b_prog, [2]=w_prog
    if (threadIdx.x == 0) { ctrl[0] = -1; ctrl[1] = -1; ctrl[2] = -1; }
    if (threadIdx.x < 32) pring[threadIdx.x] = make_float2(NEGV, NEGV);
    __syncthreads();                   // only barrier; waves drift after this

    volatile int* a_prog = &ctrl[0];
    volatile int* b_prog = &ctrl[1];
    volatile int* w_prog = &ctrl[2];

    const int blk = blockIdx.x;
    const int b = blk & (BATCH - 1);
    const int dir = blk >> 6;
    const int wid = (int)threadIdx.x >> 6;
    const int lane = (int)threadIdx.x & 63;
    const float* Sdb = Sd + (size_t)b * NM;
    float* Sout = (dir ? Sb : Sf) + (size_t)b * NM;

    if (wid == 0) {
        if (dir) dp_half<1, 0>(Sdb, b, lane, ring, pring, a_prog, b_prog, w_prog);
        else     dp_half<0, 0>(Sdb, b, lane, ring, pring, a_prog, b_prog, w_prog);
    } else if (wid == 1) {
        if (dir) dp_half<1, 1>(Sdb, b, lane, ring, pring, b_prog, a_prog, w_prog);
        else     dp_half<0, 1>(Sdb, b, lane, ring, pring, b_prog, a_prog, w_prog);
    } else {
        writer_run(Sout, b, lane, ring, a_prog, b_prog, w_prog);
    }
}

// K2': logit in skew space (logical rows; all arrays share the prow mapping).
__global__ __launch_bounds__(256) void logit_skew_kernel(float* __restrict__ Sd,
                                                         const float* __restrict__ Sf,
                                                         const float* __restrict__ Sb,
                                                         float* __restrict__ partial) {
    const size_t n4 = TOTAL / 4;
    float mx = NEGV;
    const size_t stride = (size_t)gridDim.x * blockDim.x;
    for (size_t e = (size_t)blockIdx.x * blockDim.x + threadIdx.x; e < n4; e += stride) {
        const int b = (int)(e >> 16);           // NM/4 = 65536
        const int rem = (int)(e & 65535);
        const int kp = rem >> 7;                // logical skew row
        const int r4 = (rem & 127) << 2;        // col group
        const size_t base = (size_t)b * NM;
        const size_t idx = base + (size_t)prow(b, kp) * MM + r4;
        const float4 f = *(const float4*)(Sf + idx);
        const float4 d = *(const float4*)(Sd + idx);
        const int k2 = (510 - kp) & 511;
        const float4 bb = *(const float4*)(Sb + base + (size_t)prow(b, k2) * MM + (508 - r4));
        float4 v;
        v.x = f.x + bb.w - d.x;
        v.y = f.y + bb.z - d.y;
        v.z = f.z + bb.y - d.z;
        v.w = f.w + bb.x - d.w;
        *(float4*)(Sd + idx) = v;
        mx = fmaxf(mx, fmaxf(fmaxf(v.x, v.y), fmaxf(v.z, v.w)));
    }
    float bm = blockMax256(mx);
    if (threadIdx.x == 0) partial[blockIdx.x] = bm;
}

// K3: reduce partials to one scalar
__global__ __launch_bounds__(256) void finalmax_kernel(const float* __restrict__ partial,
                                                       int n,
                                                       float* __restrict__ outmax) {
    float mx = NEGV;
    for (int i = threadIdx.x; i < n; i += 256) mx = fmaxf(mx, partial[i]);
    float bm = blockMax256(mx);
    if (threadIdx.x == 0) *outmax = bm;
}

// K4': unskew + subtract max. out[i][j] = OS[(i+j) logical][i] - mx. Tiled LDS.
__global__ __launch_bounds__(256) void unskew_kernel(const float* __restrict__ OS,
                                                     float* __restrict__ out,
                                                     const float* __restrict__ maxp) {
    __shared__ float lds[127 * 64];
    const float mx = *maxp;
    const int bi = blockIdx.x;
    const int b = bi >> 6;
    const int t = bi & 63;
    const int i0 = (t >> 3) * 64;
    const int j0 = (t & 7) * 64;
    const float* Ob = OS + (size_t)b * NM;
    float* ob = out + (size_t)b * NM;
    const int base = i0 + j0;
    {
        const int xg = ((int)threadIdx.x & 15) * 4;
        const int s0 = (int)threadIdx.x >> 4;
        for (int sw = 0; sw < 8; ++sw) {
            const int s = s0 + 16 * sw;
            if (s < 127) {
                const float4 v = *(const float4*)(Ob + (size_t)prow(b, base + s) * MM + i0 + xg);
                *(float4*)(lds + swz(s, xg)) = v;
            }
        }
    }
    __syncthreads();
    const int x4 = ((int)threadIdx.x & 15) * 4;   // j - j0 group
    const int y0 = (int)threadIdx.x >> 4;         // i - i0
    for (int sw = 0; sw < 4; ++sw) {
        const int y = y0 + 16 * sw;
        float4 v;
        v.x = lds[swz(x4 + 0 + y, y)] - mx;
        v.y = lds[swz(x4 + 1 + y, y)] - mx;
        v.z = lds[swz(x4 + 2 + y, y)] - mx;
        v.w = lds[swz(x4 + 3 + y, y)] - mx;
        *(float4*)(ob + (size_t)(i0 + y) * MM + j0 + x4) = v;
    }
}

// ===========================================================================
// LEGACY PATH (round-0, known-good): used only if ws_size < 128MB + slack.
// ===========================================================================
template <int DIR>
__device__ __forceinline__ void dp_run_legacy(const float* __restrict__ Db,
                                              float* __restrict__ Rp, int lane) {
    const int i0 = lane * 8;
    const bool l0 = (lane == 0);
    const float dgb0 = l0 ? 0.f : NEGV;

#define PTRS(r) \
    const float* ldp_##r = DIR ? (Db + (size_t)(NM - 1) - (size_t)(i0 + r) * MM) \
                               : (Db + (size_t)(i0 + r) * MM); \
    float* stp_##r = DIR ? (Rp + (size_t)(NM - 1) - (size_t)(i0 + r) * MM) \
                         : (Rp + (size_t)(i0 + r) * MM);
    PTRS(0) PTRS(1) PTRS(2) PTRS(3) PTRS(4) PTRS(5) PTRS(6) PTRS(7)

#define LOADG(r, dst, jgexpr) do { \
        int jc_ = (jgexpr); \
        jc_ = jc_ < 0 ? 0 : jc_; jc_ = jc_ > (MM - 4) ? (MM - 4) : jc_; \
        if (DIR) { const float4 t_ = *(const float4*)(ldp_##r - jc_ - 3); \
                   dst = make_float4(t_.w, t_.z, t_.y, t_.x); } \
        else     { dst = *(const float4*)(ldp_##r + jc_); } \
    } while (0)

#define INIT(r) \
    float p1_##r = NEGV, p2_##r = NEGV, p3_##r = NEGV, np_##r = NEGV; \
    float4 dc_##r, dn_##r; \
    LOADG(r, dn_##r, 0); dc_##r = dn_##r;
    INIT(0) INIT(1) INIT(2) INIT(3) INIT(4) INIT(5) INIT(6) INIT(7)

#define SWAPLOAD(r) do { dc_##r = dn_##r; LOADG(r, dn_##r, jj - (r) + 4); } while (0)

#define CELL(r, KK, DGIN, UPIN, DGB) do { \
        const int j_ = jj - (r); \
        const bool jz_ = (j_ == 0); \
        const float dg_ = jz_ ? (DGB) : (DGIN); \
        const float up_ = (UPIN); \
        const float lf_ = jz_ ? NEGV : p1_##r; \
        const float m_  = fmaxf(fmaxf(dg_, up_), lf_); \
        const float mn_ = fminf(fminf(dg_, up_), lf_); \
        const float md_ = __builtin_amdgcn_fmed3f(dg_, up_, lf_); \
        const float s_  = 1.f + __expf(mn_ - m_) + __expf(md_ - m_); \
        np_##r = F4C(dc_##r, ((KK) - (r)) & 3) + m_ + __logf(s_); \
    } while (0)

#define STORE(r) do { \
        const int j_ = jj - (r); \
        if (j_ >= 3 && j_ < MM) { \
            if (DIR) *(float4*)(stp_##r - j_) = \
                make_float4(np_##r, p1_##r, p2_##r, p3_##r); \
            else     *(float4*)(stp_##r + j_ - 3) = \
                make_float4(p3_##r, p2_##r, p1_##r, np_##r); \
        } \
    } while (0)

#define SHIFT(r) do { p3_##r = p2_##r; p2_##r = p1_##r; p1_##r = np_##r; } while (0)

#define LSTEP(KK, LA, LB, SA, SB) do { \
        const int jj = kbj + (KK); \
        SWAPLOAD(LA); SWAPLOAD(LB); \
        const float ups_ = wave_shr1(p1_7); \
        const float dgs_ = wave_shr1(p2_7); \
        const float up0r = l0 ? NEGV : ups_; \
        const float dg0r = l0 ? NEGV : dgs_; \
        CELL(0, KK, dg0r, up0r, dgb0); \
        CELL(1, KK, p2_0, p1_0, NEGV); \
        CELL(2, KK, p2_1, p1_1, NEGV); \
        CELL(3, KK, p2_2, p1_2, NEGV); \
        CELL(4, KK, p2_3, p1_3, NEGV); \
        CELL(5, KK, p2_4, p1_4, NEGV); \
        CELL(6, KK, p2_5, p1_5, NEGV); \
        CELL(7, KK, p2_6, p1_6, NEGV); \
        STORE(SA); STORE(SB); \
        SHIFT(0); SHIFT(1); SHIFT(2); SHIFT(3); \
        SHIFT(4); SHIFT(5); SHIFT(6); SHIFT(7); \
    } while (0)

    for (int kb = 0; kb < NN + MM; kb += 4) {
        const int kbj = kb - i0;
        LSTEP(0, 0, 4, 1, 5);
        LSTEP(1, 1, 5, 2, 6);
        LSTEP(2, 2, 6, 3, 7);
        LSTEP(3, 3, 7, 0, 4);
    }

#undef PTRS
#undef LOADG
#undef INIT
#undef SWAPLOAD
#undef CELL
#undef STORE
#undef SHIFT
#undef LSTEP
}

__global__ __launch_bounds__(64, 1) void dp_kernel_legacy(const float* __restrict__ D,
                                                          float* __restrict__ Rf,
                                                          float* __restrict__ Rb) {
    const int blk = blockIdx.x;
    const int b = blk & (BATCH - 1);
    const int dir = blk >> 6;
    const float* __restrict__ Db = D + (size_t)b * NM;
    const int lane = (int)threadIdx.x;
    if (dir) dp_run_legacy<1>(Db, Rb + (size_t)b * NM, lane);
    else     dp_run_legacy<0>(Db, Rf + (size_t)b * NM, lane);
}

__global__ __launch_bounds__(256) void logit_kernel(const float4* __restrict__ D,
                                                    const float4* __restrict__ Rb,
                                                    float4* __restrict__ out,
                                                    float* __restrict__ partial) {
    const size_t n4 = TOTAL / 4;
    float mx = NEGV;
    const size_t stride = (size_t)gridDim.x * blockDim.x;
    for (size_t idx = (size_t)blockIdx.x * blockDim.x + threadIdx.x; idx < n4;
         idx += stride) {
        float4 f = out[idx], bb = Rb[idx], d = D[idx];
        float4 v = make_float4(f.x + bb.x - d.x, f.y + bb.y - d.y,
                               f.z + bb.z - d.z, f.w + bb.w - d.w);
        out[idx] = v;
        mx = fmaxf(mx, fmaxf(fmaxf(v.x, v.y), fmaxf(v.z, v.w)));
    }
    float bm = blockMax256(mx);
    if (threadIdx.x == 0) partial[blockIdx.x] = bm;
}

__global__ __launch_bounds__(256) void sub_kernel(float4* __restrict__ out,
                                                  const float* __restrict__ maxp) {
    const float mx = *maxp;
    const size_t n4 = TOTAL / 4;
    const size_t stride = (size_t)gridDim.x * blockDim.x;
    for (size_t idx = (size_t)blockIdx.x * blockDim.x + threadIdx.x; idx < n4;
         idx += stride) {
        float4 v = out[idx];
        v.x -= mx; v.y -= mx; v.z -= mx; v.w -= mx;
        out[idx] = v;
    }
}

extern "C" void kernel_launch(void* const* d_in, const int* in_sizes, int n_in,
                              void* d_out, int out_size, void* d_ws, size_t ws_size,
                              hipStream_t stream) {
    const float* D = (const float*)d_in[0];
    float* out = (float*)d_out;

    const size_t needed = (2 * TOTAL + 4096) * sizeof(float);
    if (ws_size >= needed) {
        float* Sd = (float*)d_ws;
        float* Sb = Sd + TOTAL;
        float* partial = Sd + 2 * TOTAL;
        float* maxp = partial + 2048;

        skew_kernel<<<4096, 256, 0, stream>>>(D, Sd);
        dp_skew_kernel<<<128, 192, 0, stream>>>(Sd, out, Sb);
        logit_skew_kernel<<<2048, 256, 0, stream>>>(Sd, out, Sb, partial);
        finalmax_kernel<<<1, 256, 0, stream>>>(partial, 2048, maxp);
        unskew_kernel<<<4096, 256, 0, stream>>>(Sd, out, maxp);
    } else {
        float* Rb = (float*)d_ws;
        float* partial = Rb + TOTAL;
        float* maxp = partial + 2048;

        dp_kernel_legacy<<<128, 64, 0, stream>>>(D, out, Rb);
        logit_kernel<<<2048, 256, 0, stream>>>((const float4*)D, (const float4*)Rb,
                                               (float4*)out, partial);
        finalmax_kernel<<<1, 256, 0, stream>>>(partial, 2048, maxp);
        sub_kernel<<<2048, 256, 0, stream>>>((float4*)out, maxp);
    }
}